// Round 24
// baseline (49.566 us; speedup 1.0000x reference)
//
#include <hip/hip_runtime.h>
#include <stdint.h>

// shape (1,1,192,224,192) f32
#define DD 192
#define HH 224
#define WW 192
#define PLANE (HH*WW)          // 43008
#define TOTAL (DD*HH*WW)       // 8257536

#define DSEG 6                 // d-outputs per block
#define NSEG (DD/DSEG)         // 32
#define NT 64                  // ONE wave per block; no LDS, no barriers
#define HPAIRS (HH/2)          // 112 row-pairs
#define NBLOCKS (HPAIRS*NSEG)  // 3584 (%8==0 for XCD swizzle)

// NO LDS: combine reads the 5-float stride-3 window directly from global.
// Rows are wave-uniform -> SGPR-base + 32b voffset loads; L1/L2 serve the
// 5x window overlap (inputs are L3-resident: FETCH ~37 MB, R20-R22).
// Boundary replicate is folded into per-lane offsets (no selects, no OOB).

// Per-plane aggregates for 6 voxels: 2 output rows x 3 w; index = row*3 + j.
struct PP {
    float IPT[6], IPS[6], IHD[6];
    float JPT[6], JPS[6], JHD[6];
};

__global__ __launch_bounds__(NT) void ngf_main_kernel(
    const float* __restrict__ I, const float* __restrict__ J,
    float* __restrict__ partial)
{
    const float EPS2 = 0.04f;  // (2*0.1)^2 — 0.5 Sobel factor folded out

    int lane = threadIdx.x;    // 0..63

    // T1: XCD-chunked bijective swizzle (3584 % 8 == 0) — R20: FETCH 61->37 MB.
    int bid0 = blockIdx.x;
    int bid  = (bid0 & 7) * (NBLOCKS / 8) + (bid0 >> 3);

    int hb   = 2 * (bid % HPAIRS);   // output rows hb, hb+1
    int seg  = bid / HPAIRS;
    int ds   = seg * DSEG;

    // clamped source rows for the 4-row sliding window (wave-uniform)
    int srow[4];
    #pragma unroll
    for (int r = 0; r < 4; ++r)
        srow[r] = min(max(hb - 1 + r, 0), HH - 1);

    // --- lane mapping: lane covers w-positions 3*lane .. 3*lane+2 ---
    int l3   = 3 * lane;
    // replicate pad folded into the edge offsets (always in-bounds):
    int offL = l3 + ((lane == 0)  ? 0 : -1);   // lane0 reads x0 (replicate)
    int offR = l3 + ((lane == 63) ? 2 :  3);   // lane63 reads x2 (replicate)

    // Sliding 2-window combine, direct-global: stream 4 rows x 2 inputs;
    // each row's 3-wide sums/diffs computed ONCE, accumulated into both
    // output windows (row hb: b=0..2; row hb+1: b=1..3).
    auto combine = [&](int dp) -> PP {
        PP P;
        #pragma unroll
        for (int j = 0; j < 6; ++j) {
            P.IPT[j] = 0.f; P.IPS[j] = 0.f; P.IHD[j] = 0.f;
            P.JPT[j] = 0.f; P.JPS[j] = 0.f; P.JHD[j] = 0.f;
        }
        size_t poff = (size_t)dp * PLANE;
        #pragma unroll
        for (int b = 0; b < 4; ++b) {
            const float* RI = I + poff + srow[b] * WW;   // wave-uniform base
            const float* RJ = J + poff + srow[b] * WW;
            {
                float L  = RI[offL];
                float x0 = RI[l3], x1 = RI[l3 + 1], x2 = RI[l3 + 2];
                float R  = RI[offR];
                float s0 = L  + x0 + x1;
                float s1 = x0 + x1 + x2;
                float s2 = x1 + x2 + R;
                float t0 = x1 - L;
                float t1 = x2 - x0;
                float t2 = R  - x1;
                if (b <= 2) {
                    P.IPT[0] += t0; P.IPT[1] += t1; P.IPT[2] += t2;
                    P.IPS[0] += s0; P.IPS[1] += s1; P.IPS[2] += s2;
                    if (b == 0) { P.IHD[0] -= s0; P.IHD[1] -= s1; P.IHD[2] -= s2; }
                    if (b == 2) { P.IHD[0] += s0; P.IHD[1] += s1; P.IHD[2] += s2; }
                }
                if (b >= 1) {
                    P.IPT[3] += t0; P.IPT[4] += t1; P.IPT[5] += t2;
                    P.IPS[3] += s0; P.IPS[4] += s1; P.IPS[5] += s2;
                    if (b == 1) { P.IHD[3] -= s0; P.IHD[4] -= s1; P.IHD[5] -= s2; }
                    if (b == 3) { P.IHD[3] += s0; P.IHD[4] += s1; P.IHD[5] += s2; }
                }
            }
            {
                float L  = RJ[offL];
                float x0 = RJ[l3], x1 = RJ[l3 + 1], x2 = RJ[l3 + 2];
                float R  = RJ[offR];
                float s0 = L  + x0 + x1;
                float s1 = x0 + x1 + x2;
                float s2 = x1 + x2 + R;
                float t0 = x1 - L;
                float t1 = x2 - x0;
                float t2 = R  - x1;
                if (b <= 2) {
                    P.JPT[0] += t0; P.JPT[1] += t1; P.JPT[2] += t2;
                    P.JPS[0] += s0; P.JPS[1] += s1; P.JPS[2] += s2;
                    if (b == 0) { P.JHD[0] -= s0; P.JHD[1] -= s1; P.JHD[2] -= s2; }
                    if (b == 2) { P.JHD[0] += s0; P.JHD[1] += s1; P.JHD[2] += s2; }
                }
                if (b >= 1) {
                    P.JPT[3] += t0; P.JPT[4] += t1; P.JPT[5] += t2;
                    P.JPS[3] += s0; P.JPS[4] += s1; P.JPS[5] += s2;
                    if (b == 1) { P.JHD[3] -= s0; P.JHD[4] -= s1; P.JHD[5] -= s2; }
                    if (b == 3) { P.JHD[3] += s0; P.JHD[4] += s1; P.JHD[5] += s2; }
                }
            }
        }
        return P;
    };

    auto dcl = [&](int m) { return min(max(ds + m, 0), DD - 1); };

    float acc = 0.0f;
    PP p[3];

    auto ngf = [&](int k) {   // outputs (k, hb) and (k, hb+1): 6 voxels
        int sa = k % 3, sb2 = (k + 1) % 3, sc = (k + 2) % 3;
        #pragma unroll
        for (int j = 0; j < 6; ++j) {
            float Ix = p[sa].IPT[j] + p[sb2].IPT[j] + p[sc].IPT[j];
            float Iy = p[sa].IHD[j] + p[sb2].IHD[j] + p[sc].IHD[j];
            float Iz = p[sc].IPS[j] - p[sa].IPS[j];
            float Jx = p[sa].JPT[j] + p[sb2].JPT[j] + p[sc].JPT[j];
            float Jy = p[sa].JHD[j] + p[sb2].JHD[j] + p[sc].JHD[j];
            float Jz = p[sc].JPS[j] - p[sa].JPS[j];
            float Imag = fmaf(Ix, Ix, fmaf(Iy, Iy, fmaf(Iz, Iz, EPS2)));
            float Jmag = fmaf(Jx, Jx, fmaf(Jy, Jy, fmaf(Jz, Jz, EPS2)));
            float dot  = fmaf(Ix, Jx, fmaf(Iy, Jy, Iz * Jz));
            acc += 1.0f - (dot * dot) * __builtin_amdgcn_rcpf(Imag * Jmag);
        }
    };

    // --- rotation: plane m -> p[(m+1)%3]; fully unrolled so the compiler
    //     can hoist next-plane loads under current-plane compute ---
    p[0] = combine(dcl(-1));
    p[1] = combine(dcl(0));
    #pragma unroll
    for (int k = 0; k < DSEG; ++k) {
        p[(k + 2) % 3] = combine(dcl(k + 1));
        ngf(k);
    }

    // --- reduction: single wave, shuffle only ---
    #pragma unroll
    for (int o = 32; o > 0; o >>= 1)
        acc += __shfl_down(acc, o, 64);
    if (lane == 0)
        partial[bid] = acc;
}

__global__ __launch_bounds__(256) void ngf_reduce_kernel(
    const float* __restrict__ partial, float* __restrict__ out)
{
    double acc = 0.0;
    for (int i = threadIdx.x; i < NBLOCKS; i += blockDim.x)
        acc += (double)partial[i];

    #pragma unroll
    for (int o = 32; o > 0; o >>= 1)
        acc += __shfl_down(acc, o, 64);

    __shared__ double smem[4];
    int lane = threadIdx.x & 63;
    int wid  = threadIdx.x >> 6;
    if (lane == 0) smem[wid] = acc;
    __syncthreads();
    if (threadIdx.x == 0) {
        double s = smem[0] + smem[1] + smem[2] + smem[3];
        out[0] = (float)(s / (double)TOTAL);
    }
}

extern "C" void kernel_launch(void* const* d_in, const int* in_sizes, int n_in,
                              void* d_out, int out_size, void* d_ws, size_t ws_size,
                              hipStream_t stream)
{
    const float* I = (const float*)d_in[0];
    const float* J = (const float*)d_in[1];
    float* out = (float*)d_out;
    float* partial = (float*)d_ws;   // NBLOCKS floats

    ngf_main_kernel<<<NBLOCKS, NT, 0, stream>>>(I, J, partial);
    ngf_reduce_kernel<<<1, 256, 0, stream>>>(partial, out);
}

// Round 25
// 24.162 us; speedup vs baseline: 2.0514x; 2.0514x over previous
//
#include <hip/hip_runtime.h>
#include <stdint.h>

// shape (1,1,192,224,192) f32
#define DD 192
#define HH 224
#define WW 192
#define PLANE (HH*WW)          // 43008
#define TOTAL (DD*HH*WW)       // 8257536

#define DSEG 12                // d-outputs per block (R22 probe: 6 -> 12)
#define NSEG (DD/DSEG)         // 16
#define NT 64                  // ONE wave per block: no s_barrier anywhere
#define HPAIRS (HH/2)          // 112 row-pairs
#define NBLOCKS (HPAIRS*NSEG)  // 1792 (%8==0 for XCD swizzle)

#define TILEF (4*WW)           // 768 floats per input (rows hb-1..hb+2)
#define BUFF (2*TILEF)         // 1536 floats per plane-buffer (I then J)
#define NPIECE 384             // 16B pieces per plane = 64 lanes x 6 (exact)
#define GUARD 4                // head guard so lane0's [3l-1] read is in-bounds

typedef __attribute__((address_space(3))) uint32_t lds_t;
typedef __attribute__((address_space(1))) const uint32_t glb_t;

// Wave-private sync only (R21/R22 skeleton). Stage = 6 uniform width-16
// loads (384 pieces / 64 lanes exactly). WAITV6 retires exactly the oldest
// stage (read-before-write); LGKM0 before re-staging a just-read buffer
// (write-after-read: all ds_reads retired to VGPRs). No s_barrier.
// WIDTH-16 ONLY: width-12 global_load_lds corrupts data on gfx950.
#define WAITV6()  asm volatile("s_waitcnt vmcnt(6)" ::: "memory")
#define WAITV0()  asm volatile("s_waitcnt vmcnt(0)" ::: "memory")
#define LGKM0()   asm volatile("s_waitcnt lgkmcnt(0)" ::: "memory")

// Per-plane aggregates for 6 voxels: 2 output rows x 3 w; index = row*3 + j.
struct PP {
    float IPT[6], IPS[6], IHD[6];
    float JPT[6], JPS[6], JHD[6];
};

__global__ __launch_bounds__(NT) void ngf_main_kernel(
    const float* __restrict__ I, const float* __restrict__ J,
    float* __restrict__ partial)
{
    // All combine reads are b32 at (3*lane + c): 3 coprime 32 -> 2 lanes/bank
    // = conflict-free (rows uniform; row stride 192 = 0 mod 32). 12.3 KB LDS.
    __shared__ __align__(16) float lds[GUARD + 2 * BUFF + 4];
    const float EPS2 = 0.04f;  // (2*0.1)^2 — 0.5 Sobel factor folded out

    int lane = threadIdx.x;    // 0..63

    // T1: XCD-chunked bijective swizzle (1792 % 8 == 0) — R20: FETCH 61->37 MB.
    int bid0 = blockIdx.x;
    int bid  = (bid0 & 7) * (NBLOCKS / 8) + (bid0 >> 3);

    int hb   = 2 * (bid % HPAIRS);   // output rows hb, hb+1
    int seg  = bid / HPAIRS;
    int ds   = seg * DSEG;

    // --- staging: 384 float4 pieces per plane, layout [inp][4 rows][192].
    //     piece p = inp*192 + r*48 + c -> LDS float offset GUARD + 4p.
    const float* sp[6];
    int lo[6];
    #pragma unroll
    for (int m = 0; m < 6; ++m) {
        int p = lane + m * NT;             // 0..383, exact cover
        int inp = (p >= NPIECE / 2) ? 1 : 0;
        int q   = p - inp * (NPIECE / 2);
        int r   = q / 48, c = q % 48;
        int srow = min(max(hb - 1 + r, 0), HH - 1);   // replicate h-halo at load
        sp[m] = (inp ? J : I) + srow * WW + c * 4;
        lo[m] = GUARD + 4 * p;
    }

    auto stage = [&](int dp, int buf) {
        size_t poff = (size_t)dp * PLANE;
        #pragma unroll
        for (int m = 0; m < 6; ++m) {
            __builtin_amdgcn_global_load_lds((glb_t*)(sp[m] + poff),
                (lds_t*)(&lds[buf * BUFF + lo[m]]), 16, 0, 0);
        }
    };

    // --- compute mapping: lane covers w-positions 3*lane .. 3*lane+2 ---
    int l3 = 3 * lane;
    bool b0  = (lane == 0);    // true image left boundary
    bool b63 = (lane == 63);   // true image right boundary

    // Sliding 2-window combine: stream 4 staged rows; each row's 3-wide
    // sums/diffs computed ONCE, accumulated into both output windows
    // (out row hb: b=0..2; out row hb+1: b=1..3).
    auto combine = [&](int buf) -> PP {
        PP P;
        #pragma unroll
        for (int j = 0; j < 6; ++j) {
            P.IPT[j] = 0.f; P.IPS[j] = 0.f; P.IHD[j] = 0.f;
            P.JPT[j] = 0.f; P.JPS[j] = 0.f; P.JHD[j] = 0.f;
        }
        const float* base = &lds[GUARD + buf * BUFF];
        #pragma unroll
        for (int b = 0; b < 4; ++b) {
            const float* BI = base + b * WW;
            const float* BJ = BI + TILEF;
            {
                float Lr = BI[l3 - 1];
                float x0 = BI[l3], x1 = BI[l3 + 1], x2 = BI[l3 + 2];
                float Rr = BI[l3 + 3];
                float L = b0  ? x0 : Lr;   // replicate pad at w=0
                float R = b63 ? x2 : Rr;   // replicate pad at w=191
                float s0 = L  + x0 + x1;
                float s1 = x0 + x1 + x2;
                float s2 = x1 + x2 + R;
                float t0 = x1 - L;
                float t1 = x2 - x0;
                float t2 = R  - x1;
                if (b <= 2) {
                    P.IPT[0] += t0; P.IPT[1] += t1; P.IPT[2] += t2;
                    P.IPS[0] += s0; P.IPS[1] += s1; P.IPS[2] += s2;
                    if (b == 0) { P.IHD[0] -= s0; P.IHD[1] -= s1; P.IHD[2] -= s2; }
                    if (b == 2) { P.IHD[0] += s0; P.IHD[1] += s1; P.IHD[2] += s2; }
                }
                if (b >= 1) {
                    P.IPT[3] += t0; P.IPT[4] += t1; P.IPT[5] += t2;
                    P.IPS[3] += s0; P.IPS[4] += s1; P.IPS[5] += s2;
                    if (b == 1) { P.IHD[3] -= s0; P.IHD[4] -= s1; P.IHD[5] -= s2; }
                    if (b == 3) { P.IHD[3] += s0; P.IHD[4] += s1; P.IHD[5] += s2; }
                }
            }
            {
                float Lr = BJ[l3 - 1];
                float x0 = BJ[l3], x1 = BJ[l3 + 1], x2 = BJ[l3 + 2];
                float Rr = BJ[l3 + 3];
                float L = b0  ? x0 : Lr;
                float R = b63 ? x2 : Rr;
                float s0 = L  + x0 + x1;
                float s1 = x0 + x1 + x2;
                float s2 = x1 + x2 + R;
                float t0 = x1 - L;
                float t1 = x2 - x0;
                float t2 = R  - x1;
                if (b <= 2) {
                    P.JPT[0] += t0; P.JPT[1] += t1; P.JPT[2] += t2;
                    P.JPS[0] += s0; P.JPS[1] += s1; P.JPS[2] += s2;
                    if (b == 0) { P.JHD[0] -= s0; P.JHD[1] -= s1; P.JHD[2] -= s2; }
                    if (b == 2) { P.JHD[0] += s0; P.JHD[1] += s1; P.JHD[2] += s2; }
                }
                if (b >= 1) {
                    P.JPT[3] += t0; P.JPT[4] += t1; P.JPT[5] += t2;
                    P.JPS[3] += s0; P.JPS[4] += s1; P.JPS[5] += s2;
                    if (b == 1) { P.JHD[3] -= s0; P.JHD[4] -= s1; P.JHD[5] -= s2; }
                    if (b == 3) { P.JHD[3] += s0; P.JHD[4] += s1; P.JHD[5] += s2; }
                }
            }
        }
        return P;
    };

    auto dcl = [&](int m) { return min(max(ds + m, 0), DD - 1); };

    float acc = 0.0f;
    PP p[3];

    auto ngf = [&](int k) {   // outputs (k, hb) and (k, hb+1): 6 voxels
        int sa = k % 3, sb2 = (k + 1) % 3, sc = (k + 2) % 3;
        #pragma unroll
        for (int j = 0; j < 6; ++j) {
            float Ix = p[sa].IPT[j] + p[sb2].IPT[j] + p[sc].IPT[j];
            float Iy = p[sa].IHD[j] + p[sb2].IHD[j] + p[sc].IHD[j];
            float Iz = p[sc].IPS[j] - p[sa].IPS[j];
            float Jx = p[sa].JPT[j] + p[sb2].JPT[j] + p[sc].JPT[j];
            float Jy = p[sa].JHD[j] + p[sb2].JHD[j] + p[sc].JHD[j];
            float Jz = p[sc].JPS[j] - p[sa].JPS[j];
            float Imag = fmaf(Ix, Ix, fmaf(Iy, Iy, fmaf(Iz, Iz, EPS2)));
            float Jmag = fmaf(Jx, Jx, fmaf(Jy, Jy, fmaf(Jz, Jz, EPS2)));
            float dot  = fmaf(Ix, Jx, fmaf(Iy, Jy, Iz * Jz));
            acc += 1.0f - (dot * dot) * __builtin_amdgcn_rcpf(Imag * Jmag);
        }
    };

    // --- prologue ---  plane m -> buffer (m+1)&1
    stage(dcl(-1), 0);           // outstanding: {S-1}=6
    stage(dcl(0), 1);            // {S-1,S0}=12
    WAITV6();                    // plane -1 landed
    p[0] = combine(0);
    LGKM0();                     // buf0 reads retired
    stage(dcl(1), 0);            // {S0,S1}=12
    WAITV6();                    // plane 0 landed
    p[1] = combine(1);
    LGKM0();
    stage(dcl(2), 1);            // {S1,S2}=12

    #pragma unroll
    for (int k = 0; k < DSEG; ++k) {
        int buf = k & 1;                 // plane k+1 sits in buffer (k+2)&1 = k&1
        if (k < DSEG - 1) { WAITV6(); }  // retire S(k+1), keep S(k+2) in flight
        else             { WAITV0(); }   // last: drain
        __builtin_amdgcn_s_setprio(1);
        p[(k + 2) % 3] = combine(buf);
        __builtin_amdgcn_s_setprio(0);
        if (k <= DSEG - 3) {
            LGKM0();                     // this wave's buf reads retired
            stage(dcl(k + 3), buf);      // plane k+3 -> buffer (k+4)&1 = k&1 ✓
        }
        __builtin_amdgcn_s_setprio(1);
        ngf(k);
        __builtin_amdgcn_s_setprio(0);
    }

    // --- reduction: single wave, shuffle only ---
    #pragma unroll
    for (int o = 32; o > 0; o >>= 1)
        acc += __shfl_down(acc, o, 64);
    if (lane == 0)
        partial[bid] = acc;
}

__global__ __launch_bounds__(256) void ngf_reduce_kernel(
    const float* __restrict__ partial, float* __restrict__ out)
{
    double acc = 0.0;
    for (int i = threadIdx.x; i < NBLOCKS; i += blockDim.x)
        acc += (double)partial[i];

    #pragma unroll
    for (int o = 32; o > 0; o >>= 1)
        acc += __shfl_down(acc, o, 64);

    __shared__ double smem[4];
    int lane = threadIdx.x & 63;
    int wid  = threadIdx.x >> 6;
    if (lane == 0) smem[wid] = acc;
    __syncthreads();
    if (threadIdx.x == 0) {
        double s = smem[0] + smem[1] + smem[2] + smem[3];
        out[0] = (float)(s / (double)TOTAL);
    }
}

extern "C" void kernel_launch(void* const* d_in, const int* in_sizes, int n_in,
                              void* d_out, int out_size, void* d_ws, size_t ws_size,
                              hipStream_t stream)
{
    const float* I = (const float*)d_in[0];
    const float* J = (const float*)d_in[1];
    float* out = (float*)d_out;
    float* partial = (float*)d_ws;   // NBLOCKS floats

    ngf_main_kernel<<<NBLOCKS, NT, 0, stream>>>(I, J, partial);
    ngf_reduce_kernel<<<1, 256, 0, stream>>>(partial, out);
}